// Round 5
// baseline (659.901 us; speedup 1.0000x reference)
//
#include <hip/hip_runtime.h>
#include <stdint.h>

#define N_EXPERTS 8
#define D_MODEL 1024
#define D_FF 4096
#define N_TOKENS 2048
#define ASSN 4096          // N_TOKENS * TOP_K
#define ROWS 4352          // ASSN + 256 slack rows for 256-row tile overrun
#define BK 64

using bfrag = __attribute__((ext_vector_type(8))) short;   // 8 x bf16
using f32x4 = __attribute__((ext_vector_type(4))) float;
typedef unsigned short u16;

__device__ __forceinline__ u16 f2bf(float f) {
  uint32_t u = __builtin_bit_cast(uint32_t, f);
  u += 0x7fffu + ((u >> 16) & 1u);   // round-to-nearest-even
  return (u16)(u >> 16);
}

__device__ __forceinline__ void gll16(const void* g, void* l) {
  __builtin_amdgcn_global_load_lds(
      (const __attribute__((address_space(1))) void*)g,
      (__attribute__((address_space(3))) void*)l, 16, 0, 0);
}

// ---------------- setup: bucket assignments by expert ----------------
__global__ void k_setup(const int* __restrict__ eidx, const float* __restrict__ ew,
                        int* __restrict__ rowmap, int* __restrict__ arow,
                        int* __restrict__ counts, int* __restrict__ offs) {
  __shared__ int sc[N_EXPERTS], so[N_EXPERTS];
  int t = threadIdx.x;
  if (t < N_EXPERTS) sc[t] = 0;
  __syncthreads();
  for (int a = t; a < ASSN; a += 256) atomicAdd(&sc[eidx[a]], 1);
  __syncthreads();
  if (t == 0) {
    int run = 0;
    for (int e = 0; e < N_EXPERTS; e++) {
      counts[e] = sc[e]; offs[e] = run; so[e] = run; run += sc[e];
    }
  }
  __syncthreads();
  for (int a = t; a < ASSN; a += 256) {
    int e = eidx[a];
    int p = atomicAdd(&so[e], 1);
    rowmap[p] = a;
    arow[a] = p;
  }
}

// ---------------- gather x rows -> bf16 packed by expert ----------------
__global__ void k_gather(const float* __restrict__ x, const int* __restrict__ rowmap,
                         u16* __restrict__ Xg) {
  int r = blockIdx.x, t = threadIdx.x;
  uint2 o;
  if (r < ASSN) {
    int tok = rowmap[r] >> 1;   // TOP_K = 2
    float4 v = *(const float4*)(x + (size_t)tok * D_MODEL + t * 4);
    o.x = (uint32_t)f2bf(v.x) | ((uint32_t)f2bf(v.y) << 16);
    o.y = (uint32_t)f2bf(v.z) | ((uint32_t)f2bf(v.w) << 16);
  } else {
    o.x = 0u; o.y = 0u;        // zero slack rows
  }
  *(uint2*)(Xg + (size_t)r * D_MODEL + t * 4) = o;
}

// ---- transpose+convert: fp32 [K][N] -> bf16 [N][K] ----
// Each block owns a 64-row n-tile and sweeps 8 k-chunks of 64 (512 k-elems),
// so per-row writes accumulate in L2 and evict as large contiguous bursts.
// Grid: (N/64, K/512, E). LDS u32 k-pairs at odd stride 33: conflict-free.
__global__ void k_convt(const float* __restrict__ src, u16* __restrict__ dst,
                        int K, int N) {
  const int e = blockIdx.z;
  src += (size_t)e * K * N;
  dst += (size_t)e * K * N;
  const int n0 = blockIdx.x << 6;
  const int kbase = blockIdx.y << 9;
  __shared__ uint32_t T2[64 * 33];
  const int t = threadIdx.x;
  const int i4 = (t & 15) << 2;      // n base within tile
  const int q  = t >> 4;             // k-pair row 0..15
  const int n = t >> 2, seg = t & 3;
  for (int it = 0; it < 8; ++it) {
    const int k0 = kbase + (it << 6);
    if (it) __syncthreads();
    #pragma unroll
    for (int p = 0; p < 2; p++) {
      const int kp = q + (p << 4);
      const float4 r0 = *(const float4*)(src + (size_t)(k0 + 2 * kp    ) * N + n0 + i4);
      const float4 r1 = *(const float4*)(src + (size_t)(k0 + 2 * kp + 1) * N + n0 + i4);
      T2[(i4 + 0) * 33 + kp] = (uint32_t)f2bf(r0.x) | ((uint32_t)f2bf(r1.x) << 16);
      T2[(i4 + 1) * 33 + kp] = (uint32_t)f2bf(r0.y) | ((uint32_t)f2bf(r1.y) << 16);
      T2[(i4 + 2) * 33 + kp] = (uint32_t)f2bf(r0.z) | ((uint32_t)f2bf(r1.z) << 16);
      T2[(i4 + 3) * 33 + kp] = (uint32_t)f2bf(r0.w) | ((uint32_t)f2bf(r1.w) << 16);
    }
    __syncthreads();
    uint32_t w[8];
    #pragma unroll
    for (int j = 0; j < 8; j++) w[j] = T2[n * 33 + (seg << 3) + j];
    u16* d = dst + (size_t)(n0 + n) * K + k0 + (seg << 4);
    *(uint4*)d = *(uint4*)&w[0];
    *(uint4*)(d + 8) = *(uint4*)&w[4];
  }
}

// ---- GEMM1: H = silu(Xg@W1) * (Xg@W2) ----
// 256x128 tile, BK=64, 8 waves, 1 block/CU, 128 KB LDS.
// 8-slot k swizzle: phys_slot = logical_slot ^ (row&7); write side applies
// the same involution to the GLOBAL k-seg (gll16 LDS dest stays linear).
__launch_bounds__(512, 2)
__global__ void k_gemm1(const u16* __restrict__ Xg,
                        const u16* __restrict__ w1t, const u16* __restrict__ w2t,
                        const int* __restrict__ counts, const int* __restrict__ offs,
                        u16* __restrict__ H) {
  const int e = blockIdx.z, nt = blockIdx.x, mt = blockIdx.y;
  const int cnt = counts[e];
  if (mt * 256 >= cnt) return;
  const int row0 = offs[e] + mt * 256;
  const int mrem = cnt - mt * 256;
  const int n0 = nt * 128;

  __shared__ u16 As[2][256 * BK];    // 64 KB
  __shared__ u16 B1s[2][128 * BK];   // 32 KB
  __shared__ u16 B2s[2][128 * BK];   // 32 KB

  const int tid = threadIdx.x;
  const int lane = tid & 63, wave = tid >> 6;     // wave 0..7
  const int l16 = lane & 15, quad = lane >> 4;
  const int wm = (wave >> 1) << 6;                // 0,64,128,192
  const int wn = (wave & 1) << 6;                 // 0,64

  // staging: swizzled global k-seg; LDS dest linear (lane lands at row l>>3, slot l&7)
  const int swz = ((lane & 7) ^ ((lane >> 3) & 7)) << 3;
  const int arow = wave * 32 + (lane >> 3);
  const int brow = wave * 16 + (lane >> 3);

  const u16* pA  = Xg + (size_t)(row0 + arow) * D_MODEL + swz;
  const size_t ebase = (size_t)e * D_MODEL * D_FF;
  const u16* pB1 = w1t + ebase + (size_t)(n0 + brow) * D_MODEL + swz;
  const u16* pB2 = w2t + ebase + (size_t)(n0 + brow) * D_MODEL + swz;

  // read-side swizzled slots for kk=0 / kk=1
  const int sA = l16 & 7;
  const int slot0 = ((quad    ) ^ sA) << 3;
  const int slot1 = ((quad + 4) ^ sA) << 3;

  f32x4 acc1[4][4] = {};
  f32x4 acc2[4][4] = {};

#define STAGE1(buf)                                                  \
  do {                                                               \
    gll16(pA,                &As[buf][(wave * 32     ) * BK]);       \
    gll16(pA +  8 * D_MODEL, &As[buf][(wave * 32 +  8) * BK]);       \
    gll16(pA + 16 * D_MODEL, &As[buf][(wave * 32 + 16) * BK]);       \
    gll16(pA + 24 * D_MODEL, &As[buf][(wave * 32 + 24) * BK]);       \
    gll16(pB1,               &B1s[buf][(wave * 16    ) * BK]);       \
    gll16(pB1 + 8 * D_MODEL, &B1s[buf][(wave * 16 + 8) * BK]);       \
    gll16(pB2,               &B2s[buf][(wave * 16    ) * BK]);       \
    gll16(pB2 + 8 * D_MODEL, &B2s[buf][(wave * 16 + 8) * BK]);       \
    pA += BK; pB1 += BK; pB2 += BK;                                  \
  } while (0)

  STAGE1(0);
  for (int t = 0; t < 16; ++t) {
    const int c = t & 1;
    if (t < 15) {
      STAGE1(1 - c);
      asm volatile("s_waitcnt vmcnt(8)" ::: "memory");   // tile t landed
    } else {
      asm volatile("s_waitcnt vmcnt(0)" ::: "memory");
    }
    __builtin_amdgcn_sched_barrier(0);
    __builtin_amdgcn_s_barrier();
    __builtin_amdgcn_sched_barrier(0);

    // kk = 0
    bfrag a0[4], b10[4], b20[4];
    #pragma unroll
    for (int i = 0; i < 4; i++)
      a0[i] = *(const bfrag*)&As[c][(wm + i * 16 + l16) * BK + slot0];
    #pragma unroll
    for (int j = 0; j < 4; j++) {
      b10[j] = *(const bfrag*)&B1s[c][(wn + j * 16 + l16) * BK + slot0];
      b20[j] = *(const bfrag*)&B2s[c][(wn + j * 16 + l16) * BK + slot0];
    }
    asm volatile("s_waitcnt lgkmcnt(0)" ::: "memory");
    __builtin_amdgcn_sched_barrier(0);
    __builtin_amdgcn_s_setprio(1);
    #pragma unroll
    for (int i = 0; i < 4; i++) {
      #pragma unroll
      for (int j = 0; j < 4; j++) {
        acc1[i][j] = __builtin_amdgcn_mfma_f32_16x16x32_bf16(a0[i], b10[j], acc1[i][j], 0, 0, 0);
        acc2[i][j] = __builtin_amdgcn_mfma_f32_16x16x32_bf16(a0[i], b20[j], acc2[i][j], 0, 0, 0);
      }
    }
    __builtin_amdgcn_s_setprio(0);

    // kk = 1 (reads may overlap kk=0 MFMA above)
    bfrag a1[4], b11[4], b21[4];
    #pragma unroll
    for (int i = 0; i < 4; i++)
      a1[i] = *(const bfrag*)&As[c][(wm + i * 16 + l16) * BK + slot1];
    #pragma unroll
    for (int j = 0; j < 4; j++) {
      b11[j] = *(const bfrag*)&B1s[c][(wn + j * 16 + l16) * BK + slot1];
      b21[j] = *(const bfrag*)&B2s[c][(wn + j * 16 + l16) * BK + slot1];
    }
    asm volatile("s_waitcnt lgkmcnt(0)" ::: "memory");
    __builtin_amdgcn_sched_barrier(0);
    __builtin_amdgcn_s_setprio(1);
    #pragma unroll
    for (int i = 0; i < 4; i++) {
      #pragma unroll
      for (int j = 0; j < 4; j++) {
        acc1[i][j] = __builtin_amdgcn_mfma_f32_16x16x32_bf16(a1[i], b11[j], acc1[i][j], 0, 0, 0);
        acc2[i][j] = __builtin_amdgcn_mfma_f32_16x16x32_bf16(a1[i], b21[j], acc2[i][j], 0, 0, 0);
      }
    }
    __builtin_amdgcn_s_setprio(0);

    __builtin_amdgcn_sched_barrier(0);
    __builtin_amdgcn_s_barrier();                  // all reads of buf[c] done
    __builtin_amdgcn_sched_barrier(0);
  }
#undef STAGE1

  // epilogue: h = silu(g)*v, store bf16. C/D layout: col=lane&15, row=quad*4+reg
  #pragma unroll
  for (int i = 0; i < 4; i++) {
    #pragma unroll
    for (int p = 0; p < 4; p++) {
      const int mloc = wm + i * 16 + quad * 4 + p;
      if (mloc < mrem) {
        u16* dst = H + (size_t)(row0 + mloc) * D_FF + n0 + wn + l16;
        #pragma unroll
        for (int j = 0; j < 4; j++) {
          float g = acc1[i][j][p];
          float vv = acc2[i][j][p];
          float h = g / (1.0f + __expf(-g)) * vv;
          dst[j * 16] = f2bf(h);
        }
      }
    }
  }
}

// ---- GEMM2: Y[kh] = H(k-half) @ W3, 256x128 tile, BK=64, split-K x2 ----
__launch_bounds__(512, 2)
__global__ void k_gemm2(const u16* __restrict__ H, const u16* __restrict__ w3t,
                        const int* __restrict__ counts, const int* __restrict__ offs,
                        float* __restrict__ Y0, float* __restrict__ Y1) {
  const int e = blockIdx.z >> 1, khalf = blockIdx.z & 1;
  const int nt = blockIdx.x, mt = blockIdx.y;
  const int cnt = counts[e];
  if (mt * 256 >= cnt) return;
  const int row0 = offs[e] + mt * 256;
  const int mrem = cnt - mt * 256;
  const int n0 = nt * 128;
  float* __restrict__ Y = khalf ? Y1 : Y0;

  __shared__ u16 As[2][256 * BK];    // 64 KB
  __shared__ u16 Bs[2][128 * BK];    // 32 KB

  const int tid = threadIdx.x;
  const int lane = tid & 63, wave = tid >> 6;
  const int l16 = lane & 15, quad = lane >> 4;
  const int wm = (wave >> 1) << 6;
  const int wn = (wave & 1) << 6;

  const int swz = ((lane & 7) ^ ((lane >> 3) & 7)) << 3;
  const int arow = wave * 32 + (lane >> 3);
  const int brow = wave * 16 + (lane >> 3);

  const u16* pA = H + (size_t)(row0 + arow) * D_FF + khalf * 2048 + swz;
  const u16* pB = w3t + (size_t)e * D_FF * D_MODEL
                + (size_t)(n0 + brow) * D_FF + khalf * 2048 + swz;

  const int sA = l16 & 7;
  const int slot0 = ((quad    ) ^ sA) << 3;
  const int slot1 = ((quad + 4) ^ sA) << 3;

  f32x4 acc[4][4] = {};

#define STAGE2(buf)                                                  \
  do {                                                               \
    gll16(pA,               &As[buf][(wave * 32     ) * BK]);        \
    gll16(pA +  8 * D_FF,   &As[buf][(wave * 32 +  8) * BK]);        \
    gll16(pA + 16 * D_FF,   &As[buf][(wave * 32 + 16) * BK]);        \
    gll16(pA + 24 * D_FF,   &As[buf][(wave * 32 + 24) * BK]);        \
    gll16(pB,               &Bs[buf][(wave * 16    ) * BK]);         \
    gll16(pB + 8 * D_FF,    &Bs[buf][(wave * 16 + 8) * BK]);         \
    pA += BK; pB += BK;                                              \
  } while (0)

  STAGE2(0);
  for (int t = 0; t < 32; ++t) {
    const int c = t & 1;
    if (t < 31) {
      STAGE2(1 - c);
      asm volatile("s_waitcnt vmcnt(6)" ::: "memory");
    } else {
      asm volatile("s_waitcnt vmcnt(0)" ::: "memory");
    }
    __builtin_amdgcn_sched_barrier(0);
    __builtin_amdgcn_s_barrier();
    __builtin_amdgcn_sched_barrier(0);

    bfrag a0[4], b0[4];
    #pragma unroll
    for (int i = 0; i < 4; i++)
      a0[i] = *(const bfrag*)&As[c][(wm + i * 16 + l16) * BK + slot0];
    #pragma unroll
    for (int j = 0; j < 4; j++)
      b0[j] = *(const bfrag*)&Bs[c][(wn + j * 16 + l16) * BK + slot0];
    asm volatile("s_waitcnt lgkmcnt(0)" ::: "memory");
    __builtin_amdgcn_sched_barrier(0);
    __builtin_amdgcn_s_setprio(1);
    #pragma unroll
    for (int i = 0; i < 4; i++) {
      #pragma unroll
      for (int j = 0; j < 4; j++)
        acc[i][j] = __builtin_amdgcn_mfma_f32_16x16x32_bf16(a0[i], b0[j], acc[i][j], 0, 0, 0);
    }
    __builtin_amdgcn_s_setprio(0);

    bfrag a1[4], b1[4];
    #pragma unroll
    for (int i = 0; i < 4; i++)
      a1[i] = *(const bfrag*)&As[c][(wm + i * 16 + l16) * BK + slot1];
    #pragma unroll
    for (int j = 0; j < 4; j++)
      b1[j] = *(const bfrag*)&Bs[c][(wn + j * 16 + l16) * BK + slot1];
    asm volatile("s_waitcnt lgkmcnt(0)" ::: "memory");
    __builtin_amdgcn_sched_barrier(0);
    __builtin_amdgcn_s_setprio(1);
    #pragma unroll
    for (int i = 0; i < 4; i++) {
      #pragma unroll
      for (int j = 0; j < 4; j++)
        acc[i][j] = __builtin_amdgcn_mfma_f32_16x16x32_bf16(a1[i], b1[j], acc[i][j], 0, 0, 0);
    }
    __builtin_amdgcn_s_setprio(0);

    __builtin_amdgcn_sched_barrier(0);
    __builtin_amdgcn_s_barrier();
    __builtin_amdgcn_sched_barrier(0);
  }
#undef STAGE2

  #pragma unroll
  for (int i = 0; i < 4; i++) {
    #pragma unroll
    for (int p = 0; p < 4; p++) {
      const int mloc = wm + i * 16 + quad * 4 + p;
      if (mloc < mrem) {
        float* dst = Y + (size_t)(row0 + mloc) * D_MODEL + n0 + wn + l16;
        #pragma unroll
        for (int j = 0; j < 4; j++) dst[j * 16] = acc[i][j][p];
      }
    }
  }
}

// ---------------- combine: out[tok] = sum_j w_j * (Y0+Y1)[arow] ----------
__global__ void k_combine(const float* __restrict__ Y0, const float* __restrict__ Y1,
                          const int* __restrict__ arow, const float* __restrict__ ew,
                          float* __restrict__ out) {
  const int tk = blockIdx.x;
  const int d = threadIdx.x * 4;
  const int a0 = tk * 2, a1 = tk * 2 + 1;
  const int r0 = arow[a0], r1 = arow[a1];
  const float w0 = ew[a0], w1 = ew[a1];
  const float4 p0 = *(const float4*)(Y0 + (size_t)r0 * D_MODEL + d);
  const float4 q0 = *(const float4*)(Y1 + (size_t)r0 * D_MODEL + d);
  const float4 p1 = *(const float4*)(Y0 + (size_t)r1 * D_MODEL + d);
  const float4 q1 = *(const float4*)(Y1 + (size_t)r1 * D_MODEL + d);
  float4 r;
  r.x = w0 * (p0.x + q0.x) + w1 * (p1.x + q1.x);
  r.y = w0 * (p0.y + q0.y) + w1 * (p1.y + q1.y);
  r.z = w0 * (p0.z + q0.z) + w1 * (p1.z + q1.z);
  r.w = w0 * (p0.w + q0.w) + w1 * (p1.w + q1.w);
  *(float4*)(out + (size_t)tk * D_MODEL + d) = r;
}

// ---------------- launcher ----------------
extern "C" void kernel_launch(void* const* d_in, const int* in_sizes, int n_in,
                              void* d_out, int out_size, void* d_ws, size_t ws_size,
                              hipStream_t stream) {
  const float* x  = (const float*)d_in[0];
  const int* eidx = (const int*)d_in[1];
  const float* ew = (const float*)d_in[2];
  const float* w1 = (const float*)d_in[3];
  const float* w2 = (const float*)d_in[4];
  const float* w3 = (const float*)d_in[5];
  float* out = (float*)d_out;

  char* ws = (char*)d_ws;
  int*   rowmap = (int*)(ws);
  int*   arow   = (int*)(ws + 16384);
  int*   counts = (int*)(ws + 32768);
  int*   offs   = (int*)(ws + 32768 + 64);
  const size_t D0 = 65536;
  const size_t SZ_XG = (size_t)ROWS * D_MODEL * 2;             //  8,912,896
  const size_t SZ_HB = (size_t)ROWS * D_FF * 2;                // 35,651,584
  const size_t SZ_Y  = (size_t)ROWS * D_MODEL * 4;             // 17,825,792
  const size_t SZ_W  = (size_t)N_EXPERTS * D_MODEL * D_FF * 2; // 67,108,864
  u16*   Xg  = (u16*)(ws + D0);
  u16*   Hb  = (u16*)(ws + D0 + SZ_XG);
  float* Y0  = (float*)(ws + D0 + SZ_XG + SZ_HB);
  float* Y1  = (float*)(ws + D0 + SZ_XG + SZ_HB + SZ_Y);
  u16*   wt1 = (u16*)(ws + D0 + SZ_XG + SZ_HB + 2 * SZ_Y);
  u16*   wt2 = wt1 + SZ_W / 2;
  u16*   wt3 = wt1;   // aliases wt1: w1t is dead once k_gemm1 completes
  // total ws use ~215 MB

  k_setup<<<1, 256, 0, stream>>>(eidx, ew, rowmap, arow, counts, offs);
  k_gather<<<ROWS, 256, 0, stream>>>(x, rowmap, Xg);
  // pre-convert weights fp32 [K][N] -> bf16 [N][K] (transposed); per-block
  // k-sweep keeps dst rows resident in L2 -> contiguous HBM write bursts.
  k_convt<<<dim3(D_FF / 64, 2, N_EXPERTS), 256, 0, stream>>>(w1, wt1, D_MODEL, D_FF);
  k_convt<<<dim3(D_FF / 64, 2, N_EXPERTS), 256, 0, stream>>>(w2, wt2, D_MODEL, D_FF);
  k_gemm1<<<dim3(D_FF / 128, 16, N_EXPERTS), 512, 0, stream>>>(Xg, wt1, wt2, counts, offs, Hb);
  k_convt<<<dim3(D_MODEL / 64, 8, N_EXPERTS), 256, 0, stream>>>(w3, wt3, D_FF, D_MODEL);
  k_gemm2<<<dim3(D_MODEL / 128, 16, N_EXPERTS * 2), 512, 0, stream>>>(Hb, wt3, counts, offs, Y0, Y1);
  k_combine<<<N_TOKENS, 256, 0, stream>>>(Y0, Y1, arow, ew, out);
}